// Round 2
// baseline (413.317 us; speedup 1.0000x reference)
//
#include <hip/hip_runtime.h>

static constexpr int T_LEN = 512;

__device__ __forceinline__ float fsigm(float x) {
    return __builtin_amdgcn_rcpf(1.0f + __expf(-x));
}
__device__ __forceinline__ float ftanh(float x) {
    return 1.0f - 2.0f * __builtin_amdgcn_rcpf(1.0f + __expf(2.0f * x));
}

// One wave = ONE batch element (64 lanes).
// Lane (j = lane&15, s = lane>>4): gate-unit j, K-quarter s of every dot product.
// Reductions: 2-step butterfly (xor 16, xor 32). h-broadcast: 4 shfl per layer.
// Weights in VGPRs. No LDS, no barriers. 2048 waves -> 8 waves/CU (2/SIMD).
__global__ __launch_bounds__(256) void gru2_fused(
    const float* __restrict__ x,
    const float* __restrict__ Wih0, const float* __restrict__ Whh0,
    const float* __restrict__ bih0, const float* __restrict__ bhh0,
    const float* __restrict__ Wih1, const float* __restrict__ Whh1,
    const float* __restrict__ bih1, const float* __restrict__ bhh1,
    const float* __restrict__ fcw,  const float* __restrict__ fcb,
    float* __restrict__ out)
{
    const int tid  = threadIdx.x;
    const int lane = tid & 63;
    const int b    = blockIdx.x * 4 + (tid >> 6);
    const int j    = lane & 15;   // gate unit
    const int s    = lane >> 4;   // K-quarter (0..3)

    // ---- per-lane weight registers ----
    float wih0[3][8], whh0[3][4], wih1[3][4], whh1[3][4];
    float bi0[3], bh0[3], bi1[3], bh1[3];
#pragma unroll
    for (int g = 0; g < 3; ++g) {
        const int row = g * 16 + j;
        {
            const float* p = Wih0 + row * 32 + 8 * s;
#pragma unroll
            for (int q = 0; q < 2; ++q) {
                float4 v = *(const float4*)(p + 4 * q);
                wih0[g][4*q+0] = v.x; wih0[g][4*q+1] = v.y;
                wih0[g][4*q+2] = v.z; wih0[g][4*q+3] = v.w;
            }
        }
        {
            float4 v = *(const float4*)(Whh0 + row * 16 + 4 * s);
            whh0[g][0] = v.x; whh0[g][1] = v.y; whh0[g][2] = v.z; whh0[g][3] = v.w;
        }
        {
            float4 v = *(const float4*)(Wih1 + row * 16 + 4 * s);
            wih1[g][0] = v.x; wih1[g][1] = v.y; wih1[g][2] = v.z; wih1[g][3] = v.w;
        }
        {
            float4 v = *(const float4*)(Whh1 + row * 16 + 4 * s);
            whh1[g][0] = v.x; whh1[g][1] = v.y; whh1[g][2] = v.z; whh1[g][3] = v.w;
        }
        bi0[g] = bih0[row]; bh0[g] = bhh0[row];
        bi1[g] = bih1[row]; bh1[g] = bhh1[row];
    }

    // ---- state ----
    float h0q[4], h1q[4];
#pragma unroll
    for (int k = 0; k < 4; ++k) { h0q[k] = 0.f; h1q[k] = 0.f; }
    float h0self = 0.f, h1self = 0.f;

    const float* xb = x + ((size_t)b * T_LEN) * 32 + 8 * s;

    // 2-deep x prefetch ring (8 floats per step per lane)
    float4 bufA[2], bufB[2];
#pragma unroll
    for (int q = 0; q < 2; ++q) {
        bufA[q] = *(const float4*)(xb + 0 * 32 + 4 * q);
        bufB[q] = *(const float4*)(xb + 1 * 32 + 4 * q);
    }

#define RED2(v) do { v += __shfl_xor(v, 16, 64); v += __shfl_xor(v, 32, 64); } while (0)

    auto step = [&](float4 (&buf)[2], int tnext) {
        // layer-0 input-gate partials from x (K-quarter: 8 of 32)
        float xa0 = 0.f, xa1 = 0.f, xa2 = 0.f;
#pragma unroll
        for (int q = 0; q < 2; ++q) {
            float4 v = buf[q];
            xa0 = fmaf(wih0[0][4*q+0], v.x, xa0);
            xa0 = fmaf(wih0[0][4*q+1], v.y, xa0);
            xa0 = fmaf(wih0[0][4*q+2], v.z, xa0);
            xa0 = fmaf(wih0[0][4*q+3], v.w, xa0);
            xa1 = fmaf(wih0[1][4*q+0], v.x, xa1);
            xa1 = fmaf(wih0[1][4*q+1], v.y, xa1);
            xa1 = fmaf(wih0[1][4*q+2], v.z, xa1);
            xa1 = fmaf(wih0[1][4*q+3], v.w, xa1);
            xa2 = fmaf(wih0[2][4*q+0], v.x, xa2);
            xa2 = fmaf(wih0[2][4*q+1], v.y, xa2);
            xa2 = fmaf(wih0[2][4*q+2], v.z, xa2);
            xa2 = fmaf(wih0[2][4*q+3], v.w, xa2);
        }
        // prefetch for t+2
#pragma unroll
        for (int q = 0; q < 2; ++q)
            buf[q] = *(const float4*)(xb + tnext * 32 + 4 * q);

        // recurrent partials: layer0 (h0) and layer1 (h1, pre-update state)
        float ha0 = 0.f, ha1 = 0.f, ha2 = 0.f;
        float hc0 = 0.f, hc1 = 0.f, hc2 = 0.f;
#pragma unroll
        for (int k = 0; k < 4; ++k) {
            ha0 = fmaf(whh0[0][k], h0q[k], ha0);
            ha1 = fmaf(whh0[1][k], h0q[k], ha1);
            ha2 = fmaf(whh0[2][k], h0q[k], ha2);
            hc0 = fmaf(whh1[0][k], h1q[k], hc0);
            hc1 = fmaf(whh1[1][k], h1q[k], hc1);
            hc2 = fmaf(whh1[2][k], h1q[k], hc2);
        }

        // butterfly reduce all 9 partials (independent, pipelined)
        RED2(xa0); RED2(xa1); RED2(xa2);
        RED2(ha0); RED2(ha1); RED2(ha2);
        RED2(hc0); RED2(hc1); RED2(hc2);

        // layer-0 gates + update (unit j, replicated across s)
        float r = fsigm((xa0 + bi0[0]) + (ha0 + bh0[0]));
        float z = fsigm((xa1 + bi0[1]) + (ha1 + bh0[1]));
        float n = ftanh((xa2 + bi0[2]) + r * (ha2 + bh0[2]));
        h0self = (1.f - z) * n + z * h0self;

        // broadcast new h0 quarter (units 4s..4s+3 live in lanes 4s..4s+3)
#pragma unroll
        for (int k = 0; k < 4; ++k)
            h0q[k] = __shfl(h0self, 4 * s + k, 64);

        // layer-1 input gates from new h0
        float ya0 = 0.f, ya1 = 0.f, ya2 = 0.f;
#pragma unroll
        for (int k = 0; k < 4; ++k) {
            ya0 = fmaf(wih1[0][k], h0q[k], ya0);
            ya1 = fmaf(wih1[1][k], h0q[k], ya1);
            ya2 = fmaf(wih1[2][k], h0q[k], ya2);
        }
        RED2(ya0); RED2(ya1); RED2(ya2);

        // layer-1 gates + update
        float r1 = fsigm((ya0 + bi1[0]) + (hc0 + bh1[0]));
        float z1 = fsigm((ya1 + bi1[1]) + (hc1 + bh1[1]));
        float n1 = ftanh((ya2 + bi1[2]) + r1 * (hc2 + bh1[2]));
        h1self = (1.f - z1) * n1 + z1 * h1self;

#pragma unroll
        for (int k = 0; k < 4; ++k)
            h1q[k] = __shfl(h1self, 4 * s + k, 64);
    };

    for (int t = 0; t < T_LEN; t += 2) {
        int tn0 = (t + 2 < T_LEN) ? (t + 2) : (T_LEN - 1);
        int tn1 = (t + 3 < T_LEN) ? (t + 3) : (T_LEN - 1);
        step(bufA, tn0);
        step(bufB, tn1);
    }

    // ---- final FC: out[b] = fc_w . h1_final + fc_b ----
    float part = 0.f;
#pragma unroll
    for (int k = 0; k < 4; ++k)
        part = fmaf(fcw[4 * s + k], h1q[k], part);
    RED2(part);
    if (lane == 0) out[b] = part + fcb[0];
#undef RED2
}

extern "C" void kernel_launch(void* const* d_in, const int* in_sizes, int n_in,
                              void* d_out, int out_size, void* d_ws, size_t ws_size,
                              hipStream_t stream) {
    const float* x    = (const float*)d_in[0];
    const float* Wih0 = (const float*)d_in[1];
    const float* Whh0 = (const float*)d_in[2];
    const float* bih0 = (const float*)d_in[3];
    const float* bhh0 = (const float*)d_in[4];
    const float* Wih1 = (const float*)d_in[5];
    const float* Whh1 = (const float*)d_in[6];
    const float* bih1 = (const float*)d_in[7];
    const float* bhh1 = (const float*)d_in[8];
    const float* fcw  = (const float*)d_in[9];
    const float* fcb  = (const float*)d_in[10];

    // 2048 batch elems, 1 per wave, 4 waves per block -> 512 blocks x 256 threads
    gru2_fused<<<512, 256, 0, stream>>>(x, Wih0, Whh0, bih0, bhh0,
                                        Wih1, Whh1, bih1, bhh1, fcw, fcb,
                                        (float*)d_out);
}

// Round 3
// 280.886 us; speedup vs baseline: 1.4715x; 1.4715x over previous
//
#include <hip/hip_runtime.h>

static constexpr int T_LEN = 512;

__device__ __forceinline__ float fsigm(float x) {
    return __builtin_amdgcn_rcpf(1.0f + __expf(-x));
}
__device__ __forceinline__ float ftanh(float x) {
    return 1.0f - 2.0f * __builtin_amdgcn_rcpf(1.0f + __expf(2.0f * x));
}
// Rotate by 1 lane within each 16-lane row, at VALU speed (no LDS/DS op).
__device__ __forceinline__ float ror1(float v) {
    int i = __builtin_bit_cast(int, v);
    i = __builtin_amdgcn_mov_dpp(i, 0x121, 0xf, 0xf, true);  // row_ror:1
    return __builtin_bit_cast(float, i);
}

// Block = 256 threads = 4 waves, 8 batches.
// Waves 0,1: layer-0 for batches 0-7 (16 lanes/batch, lane j owns unit j).
// Waves 2,3: layer-1 for batches 0-7, one step behind (software pipeline).
// h state stays distributed (1 unit/lane); recurrent matvecs use a DPP
// row_ror:1 systolic chain with rotation-permuted weights -> ZERO DS ops
// in the dot products. Only cross-wave traffic: h0 via 1KB LDS double
// buffer + 1 barrier/step.
__global__ __launch_bounds__(256, 1) void gru2_pipe(
    const float* __restrict__ x,
    const float* __restrict__ Wih0, const float* __restrict__ Whh0,
    const float* __restrict__ bih0, const float* __restrict__ bhh0,
    const float* __restrict__ Wih1, const float* __restrict__ Whh1,
    const float* __restrict__ bih1, const float* __restrict__ bhh1,
    const float* __restrict__ fcw,  const float* __restrict__ fcb,
    float* __restrict__ out)
{
    const int tid  = threadIdx.x;
    const int w    = tid >> 6;        // wave in block (0..3)
    const int lane = tid & 63;
    const int j    = lane & 15;       // unit index
    const int bb   = (w & 1) * 4 + (lane >> 4);  // batch within block (0..7)
    const int b    = blockIdx.x * 8 + bb;
    const bool isL0 = (w < 2);

    __shared__ float h0buf[2][8][16];

    // ---- rotation-direction probe (direction-agnostic weight layout) ----
    const int d = (((int)ror1((float)j)) - j) & 15;   // lane shift per ror1

    // ---- per-lane weights (role-dependent, shared register arrays) ----
    // wbig: L0 -> W_ih0 rows (len 32, natural order); L1 -> W_ih1 rotated (len 16)
    // wrec: rotated W_hh rows (len 16)
    float wbig[3][32];
    float wrec[3][16];
    float b_r, b_z, b_in, b_hn;

    if (isL0) {
#pragma unroll
        for (int g = 0; g < 3; ++g) {
            const int row = g * 16 + j;
#pragma unroll
            for (int m = 0; m < 32; ++m)
                wbig[g][m] = Wih0[row * 32 + m];
#pragma unroll
            for (int m = 0; m < 16; ++m)
                wrec[g][m] = Whh0[row * 16 + ((j + m * d) & 15)];
        }
        b_r  = bih0[j]      + bhh0[j];
        b_z  = bih0[16 + j] + bhh0[16 + j];
        b_in = bih0[32 + j];
        b_hn = bhh0[32 + j];
    } else {
#pragma unroll
        for (int g = 0; g < 3; ++g) {
            const int row = g * 16 + j;
#pragma unroll
            for (int m = 0; m < 16; ++m) {
                wbig[g][m] = Wih1[row * 16 + ((j + m * d) & 15)];
                wrec[g][m] = Whh1[row * 16 + ((j + m * d) & 15)];
            }
        }
        b_r  = bih1[j]      + bhh1[j];
        b_z  = bih1[16 + j] + bhh1[16 + j];
        b_in = bih1[32 + j];
        b_hn = bhh1[32 + j];
    }

    float hs = 0.f;   // L0: h0_j ; L1: h1_j  (distributed state)

    const float* xbase = x + (size_t)b * T_LEN * 32;

    // ---- 2-deep x prefetch ring (L0 waves only) ----
    float4 xA[8], xB[8];
    if (isL0) {
#pragma unroll
        for (int q = 0; q < 8; ++q) {
            xA[q] = *(const float4*)(xbase + 0 * 32 + 4 * q);
            xB[q] = *(const float4*)(xbase + 1 * 32 + 4 * q);
        }
    }

    auto l0_step = [&](float4 (&xb)[8], int i) {
        // x-gate dots (full length-32 per lane)
        float xr = 0.f, xz = 0.f, xn = 0.f;
#pragma unroll
        for (int q = 0; q < 8; ++q) {
            float4 v = xb[q];
            xr = fmaf(wbig[0][4*q+0], v.x, xr);
            xr = fmaf(wbig[0][4*q+1], v.y, xr);
            xr = fmaf(wbig[0][4*q+2], v.z, xr);
            xr = fmaf(wbig[0][4*q+3], v.w, xr);
            xz = fmaf(wbig[1][4*q+0], v.x, xz);
            xz = fmaf(wbig[1][4*q+1], v.y, xz);
            xz = fmaf(wbig[1][4*q+2], v.z, xz);
            xz = fmaf(wbig[1][4*q+3], v.w, xz);
            xn = fmaf(wbig[2][4*q+0], v.x, xn);
            xn = fmaf(wbig[2][4*q+1], v.y, xn);
            xn = fmaf(wbig[2][4*q+2], v.z, xn);
            xn = fmaf(wbig[2][4*q+3], v.w, xn);
        }
        // prefetch t = i+2 into the same buffer
        const int t2 = (i + 2 <= T_LEN - 1) ? (i + 2) : (T_LEN - 1);
#pragma unroll
        for (int q = 0; q < 8; ++q)
            xb[q] = *(const float4*)(xbase + (size_t)t2 * 32 + 4 * q);

        // recurrent dots via DPP systolic rotation of h0 (no DS ops)
        float ar = 0.f, az = 0.f, an = 0.f, tt = hs;
#pragma unroll
        for (int m = 0; m < 16; ++m) {
            ar = fmaf(wrec[0][m], tt, ar);
            az = fmaf(wrec[1][m], tt, az);
            an = fmaf(wrec[2][m], tt, an);
            if (m < 15) tt = ror1(tt);
        }

        float r = fsigm(xr + ar + b_r);
        float z = fsigm(xz + az + b_z);
        float n = ftanh(xn + b_in + r * (an + b_hn));
        hs = fmaf(z, hs - n, n);

        h0buf[i & 1][bb][j] = hs;
    };

    auto l1_step = [&](int i) {   // computes h1 for t = i-1
        float u = h0buf[(i - 1) & 1][bb][j];  // h0[t] distributed
        float yr = 0.f, yz = 0.f, yn = 0.f;
        float hr = 0.f, hz = 0.f, hn = 0.f;
        float vv = hs;
#pragma unroll
        for (int m = 0; m < 16; ++m) {
            yr = fmaf(wbig[0][m], u, yr);
            yz = fmaf(wbig[1][m], u, yz);
            yn = fmaf(wbig[2][m], u, yn);
            hr = fmaf(wrec[0][m], vv, hr);
            hz = fmaf(wrec[1][m], vv, hz);
            hn = fmaf(wrec[2][m], vv, hn);
            if (m < 15) { u = ror1(u); vv = ror1(vv); }
        }
        float r = fsigm(yr + hr + b_r);
        float z = fsigm(yz + hz + b_z);
        float n = ftanh(yn + b_in + r * (hn + b_hn));
        hs = fmaf(z, hs - n, n);
    };

    // ---- pipelined loop: L0 does step i, L1 does step i-1 ----
    if (isL0) l0_step(xA, 0);
    __syncthreads();
#pragma unroll 1
    for (int i = 1; i < T_LEN; i += 2) {
        // odd i
        if (isL0) l0_step(xB, i);
        else      l1_step(i);
        __syncthreads();
        // even i+1 (last pair: i+1 == T_LEN -> L0 done, L1 drains)
        if (isL0) { if (i + 1 < T_LEN) l0_step(xA, i + 1); }
        else      l1_step(i + 1);
        __syncthreads();
    }

    // ---- FC on final h1 (L1 waves hold it distributed) ----
    if (!isL0) {
        float p = fcw[j] * hs;
        p += __shfl_xor(p, 1);
        p += __shfl_xor(p, 2);
        p += __shfl_xor(p, 4);
        p += __shfl_xor(p, 8);
        if (j == 0) out[b] = p + fcb[0];
    }
}

extern "C" void kernel_launch(void* const* d_in, const int* in_sizes, int n_in,
                              void* d_out, int out_size, void* d_ws, size_t ws_size,
                              hipStream_t stream) {
    const float* x    = (const float*)d_in[0];
    const float* Wih0 = (const float*)d_in[1];
    const float* Whh0 = (const float*)d_in[2];
    const float* bih0 = (const float*)d_in[3];
    const float* bhh0 = (const float*)d_in[4];
    const float* Wih1 = (const float*)d_in[5];
    const float* Whh1 = (const float*)d_in[6];
    const float* bih1 = (const float*)d_in[7];
    const float* bhh1 = (const float*)d_in[8];
    const float* fcw  = (const float*)d_in[9];
    const float* fcb  = (const float*)d_in[10];

    // 2048 batches, 8 per block -> 256 blocks x 256 threads (1 block/CU)
    gru2_pipe<<<256, 256, 0, stream>>>(x, Wih0, Whh0, bih0, bhh0,
                                       Wih1, Whh1, bih1, bhh1, fcw, fcb,
                                       (float*)d_out);
}